// Round 5
// baseline (582.889 us; speedup 1.0000x reference)
//
#include <hip/hip_runtime.h>
#include <hip/hip_fp16.h>

// CRF NLL, B=8192, T=512, NT=7.
// Kernel A: thread = (row, 16-step chunk): 7x7 linear-domain operator in regs,
//           rescaled, stored f16 to ws in [c][k][r] layout (B-coalesced).
// Kernel B: lane = row: serially chains 32 operators (49 fma each, reg
//           double-buffered coalesced loads), adds start/end/num terms,
//           wave-reduces, atomicAdd.

#define Bsz 8192
#define Tsz 512
#define NTG 7
#define NCH 32
#define CS  16

__device__ __forceinline__ float rfl(float x) {
    return __int_as_float(__builtin_amdgcn_readfirstlane(__float_as_int(x)));
}

__global__ __launch_bounds__(256, 4) void crf_op_kernel(
    const float* __restrict__ em, const int* __restrict__ labels,
    const int* __restrict__ mask, const float* __restrict__ startT,
    const float* __restrict__ trans,
    __half* __restrict__ Mh, float* __restrict__ lsbuf,
    float* __restrict__ numbuf, int* __restrict__ cntbuf)
{
    const int tid = blockIdx.x * blockDim.x + threadIdx.x;
    const int c = tid & (NCH - 1);   // chunk: varies across lanes (coalesced-ish em reads)
    const int r = tid >> 5;          // row

    __shared__ float transS[49];
    if (threadIdx.x < 49) transS[threadIdx.x] = trans[threadIdx.x];
    __syncthreads();

    // W = exp(trans), wave-uniform -> SGPRs
    float W[49];
#pragma unroll
    for (int k = 0; k < 49; ++k) W[k] = rfl(__expf(trans[k]));

    float M[49];
#pragma unroll
    for (int k = 0; k < 49; ++k) M[k] = 0.0f;
#pragma unroll
    for (int i = 0; i < 7; ++i) M[i * 7 + i] = 1.0f;

    float logscale = 0.0f, num = 0.0f;
    int cnt = 0;

    const int t0 = c * CS;
    const float* emr  = em + (size_t)r * (Tsz * NTG) + (size_t)t0 * NTG;
    const int*   labr = labels + r * Tsz + t0;
    const int*   mskr = mask   + r * Tsz + t0;

    int lprev = 0;
    if (c > 0) { lprev = labr[-1]; if (lprev < 0) lprev = 0; }

#pragma unroll
    for (int g = 0; g < CS / 4; ++g) {
        // 4 timesteps = 28 floats; explicit unpack -> guaranteed registers
        float er[28];
        const float4* ep = (const float4*)(emr + g * 28);
#pragma unroll
        for (int q = 0; q < 7; ++q) {
            float4 v = ep[q];
            er[4 * q + 0] = v.x; er[4 * q + 1] = v.y;
            er[4 * q + 2] = v.z; er[4 * q + 3] = v.w;
        }
        int4 lab4 = *(const int4*)(labr + g * 4);
        int4 msk4 = *(const int4*)(mskr + g * 4);
        int labs[4] = {lab4.x, lab4.y, lab4.z, lab4.w};
        int msks[4] = {msk4.x, msk4.y, msk4.z, msk4.w};

#pragma unroll
        for (int s = 0; s < 4; ++s) {
            const int tt = t0 + g * 4 + s;
            int lc = labs[s]; if (lc < 0) lc = 0;
            const float mf = (float)msks[s];
            cnt += msks[s];

            float esel = er[s * 7 + 0];
#pragma unroll
            for (int j = 1; j < 7; ++j) esel = (lc == j) ? er[s * 7 + j] : esel;

            if (tt == 0) {
                num += startT[lc] + esel;
            } else {
                num += mf * (transS[lprev * 7 + lc] + esel);
                if (msks[s] > 0) {
                    float e[7];
#pragma unroll
                    for (int j = 0; j < 7; ++j) e[j] = __expf(er[s * 7 + j]);
#pragma unroll
                    for (int i = 0; i < 7; ++i) {
                        float tmp[7];
#pragma unroll
                        for (int j = 0; j < 7; ++j) tmp[j] = 0.0f;
#pragma unroll
                        for (int k = 0; k < 7; ++k) {
                            const float mik = M[i * 7 + k];
#pragma unroll
                            for (int j = 0; j < 7; ++j)
                                tmp[j] = fmaf(mik, W[k * 7 + j], tmp[j]);
                        }
#pragma unroll
                        for (int j = 0; j < 7; ++j) M[i * 7 + j] = tmp[j] * e[j];
                    }
                }
            }
            lprev = lc;
        }
        if (g & 1) {   // rescale every 8 steps; final g=3 normalizes pre-store
            float mx = 1e-30f;
#pragma unroll
            for (int k = 0; k < 49; ++k) mx = fmaxf(mx, M[k]);
            const float inv = 1.0f / mx;
#pragma unroll
            for (int k = 0; k < 49; ++k) M[k] *= inv;
            logscale += __logf(mx);
        }
    }

    // [c][k][r] layout: B reads coalesced; A's scattered stores are amortized
#pragma unroll
    for (int k = 0; k < 49; ++k)
        Mh[((size_t)c * 49 + k) * Bsz + r] = __float2half(M[k]);
    lsbuf[c * Bsz + r]  = logscale;
    numbuf[c * Bsz + r] = num;
    cntbuf[c * Bsz + r] = cnt;
}

__global__ __launch_bounds__(64, 1) void crf_chain_kernel(
    const float* __restrict__ em, const int* __restrict__ labels,
    const float* __restrict__ startT, const float* __restrict__ endT,
    const __half* __restrict__ Mh, const float* __restrict__ lsbuf,
    const float* __restrict__ numbuf, const int* __restrict__ cntbuf,
    float* __restrict__ out)
{
    const int r = blockIdx.x * 64 + threadIdx.x;

    float va[7];
#pragma unroll
    for (int j = 0; j < 7; ++j)
        va[j] = __expf(startT[j] + em[(size_t)r * (Tsz * NTG) + j]);

    float ls = 0.0f, num = 0.0f;
    int cnt = 0;

    float bufA[49], bufB[49];

#define LOADC(buf, cc) {                                                   \
    const int _c = (cc);                                                   \
    _Pragma("unroll")                                                      \
    for (int k = 0; k < 49; ++k)                                           \
        buf[k] = __half2float(Mh[((size_t)_c * 49 + k) * Bsz + r]);        \
    ls  += lsbuf[_c * Bsz + r];                                            \
    num += numbuf[_c * Bsz + r];                                           \
    cnt += cntbuf[_c * Bsz + r]; }

#define STEP(buf) {                                                        \
    float nv[7];                                                           \
    _Pragma("unroll")                                                      \
    for (int j = 0; j < 7; ++j) nv[j] = 0.0f;                              \
    _Pragma("unroll")                                                      \
    for (int i = 0; i < 7; ++i) {                                          \
        const float vi = va[i];                                            \
        _Pragma("unroll")                                                  \
        for (int j = 0; j < 7; ++j)                                        \
            nv[j] = fmaf(vi, buf[i * 7 + j], nv[j]);                       \
    }                                                                      \
    float mx = 1e-30f;                                                     \
    _Pragma("unroll")                                                      \
    for (int j = 0; j < 7; ++j) mx = fmaxf(mx, nv[j]);                     \
    const float inv = 1.0f / mx;                                           \
    _Pragma("unroll")                                                      \
    for (int j = 0; j < 7; ++j) va[j] = nv[j] * inv;                       \
    ls += __logf(mx); }

    LOADC(bufA, 0);
    for (int p = 0; p < NCH / 2; ++p) {
        LOADC(bufB, 2 * p + 1);
        STEP(bufA);
        if (p < NCH / 2 - 1) LOADC(bufA, 2 * p + 2);
        STEP(bufB);
    }
#undef LOADC
#undef STEP

    float dsum = 0.0f;
#pragma unroll
    for (int j = 0; j < 7; ++j) dsum += va[j] * __expf(endT[j]);
    const float den = ls + __logf(dsum);

    int se = cnt - 1; if (se < 0) se = 0;
    int lt = labels[r * Tsz + se]; if (lt < 0) lt = 0;
    num += endT[lt];

    float val = den - num;
#pragma unroll
    for (int m = 1; m < 64; m <<= 1) val += __shfl_xor(val, m, 64);
    if (threadIdx.x == 0) atomicAdd(out, val);
}

extern "C" void kernel_launch(void* const* d_in, const int* in_sizes, int n_in,
                              void* d_out, int out_size, void* d_ws, size_t ws_size,
                              hipStream_t stream) {
    const float* em     = (const float*)d_in[0];
    const int*   labels = (const int*)d_in[1];
    const int*   mask   = (const int*)d_in[2];
    const float* startT = (const float*)d_in[3];
    const float* endT   = (const float*)d_in[4];
    const float* trans  = (const float*)d_in[5];
    float* out = (float*)d_out;

    __half* Mh    = (__half*)d_ws;                          // 32*49*8192*2B = 25.7MB
    float*  lsbuf = (float*)(Mh + (size_t)NCH * 49 * Bsz);  // 1MB
    float*  numbuf = lsbuf + (size_t)NCH * Bsz;             // 1MB
    int*    cntbuf = (int*)(numbuf + (size_t)NCH * Bsz);    // 1MB
    (void)in_sizes; (void)n_in; (void)out_size; (void)ws_size;

    hipMemsetAsync(out, 0, sizeof(float), stream);

    crf_op_kernel<<<(Bsz * NCH) / 256, 256, 0, stream>>>(
        em, labels, mask, startT, trans, Mh, lsbuf, numbuf, cntbuf);
    crf_chain_kernel<<<Bsz / 64, 64, 0, stream>>>(
        em, labels, startT, endT, Mh, lsbuf, numbuf, cntbuf, out);
}

// Round 6
// 430.467 us; speedup vs baseline: 1.3541x; 1.3541x over previous
//
#include <hip/hip_runtime.h>
#include <hip/hip_fp16.h>

// CRF NLL, B=8192, T=512, NT=7.
// Kernel A: thread = (row, 16-step chunk): 7x7 linear-domain operator in regs,
//           rescaled, stored f16 to ws [c][k][r] (r lane-consecutive -> coalesced).
// Kernel B: lane = row: chains 32 operators (63 fma each, reg double-buffered
//           coalesced loads), adds start/end/num terms, wave-reduce, atomicAdd.

#define Bsz 8192
#define Tsz 512
#define NTG 7
#define NCH 32
#define CS  16

__device__ __forceinline__ float rfl(float x) {
    return __int_as_float(__builtin_amdgcn_readfirstlane(__float_as_int(x)));
}

__global__ __launch_bounds__(256) void crf_op_kernel(
    const float* __restrict__ em, const int* __restrict__ labels,
    const int* __restrict__ mask, const float* __restrict__ startT,
    const float* __restrict__ trans,
    __half* __restrict__ Mh, float* __restrict__ lsbuf,
    float* __restrict__ numbuf, int* __restrict__ cntbuf)
{
    const int tid = blockIdx.x * blockDim.x + threadIdx.x;
    const int r = tid & (Bsz - 1);   // row: lane-consecutive -> coalesced ws stores
    const int c = tid >> 13;         // chunk: uniform per block

    __shared__ float transS[49];
    if (threadIdx.x < 49) transS[threadIdx.x] = trans[threadIdx.x];
    __syncthreads();

    // W = exp(trans), wave-uniform -> SGPRs
    float W[49];
#pragma unroll
    for (int k = 0; k < 49; ++k) W[k] = rfl(__expf(trans[k]));

    float M[49];
#pragma unroll
    for (int k = 0; k < 49; ++k) M[k] = 0.0f;
#pragma unroll
    for (int i = 0; i < 7; ++i) M[i * 7 + i] = 1.0f;

    float logscale = 0.0f, num = 0.0f;
    int cnt = 0;

    const int t0 = c * CS;
    const float* emr  = em + (size_t)r * (Tsz * NTG) + (size_t)t0 * NTG; // 448B-aligned
    const int*   labr = labels + r * Tsz + t0;
    const int*   mskr = mask   + r * Tsz + t0;

    int lprev = 0;
    if (c > 0) { lprev = labr[-1]; if (lprev < 0) lprev = 0; }

#pragma unroll
    for (int g = 0; g < CS / 4; ++g) {
        // 4 timesteps = 28 floats; explicit unpack -> guaranteed registers
        float er[28];
        const float4* ep = (const float4*)(emr + g * 28);
#pragma unroll
        for (int q = 0; q < 7; ++q) {
            float4 v = ep[q];
            er[4 * q + 0] = v.x; er[4 * q + 1] = v.y;
            er[4 * q + 2] = v.z; er[4 * q + 3] = v.w;
        }
        int4 lab4 = *(const int4*)(labr + g * 4);
        int4 msk4 = *(const int4*)(mskr + g * 4);
        int labs[4] = {lab4.x, lab4.y, lab4.z, lab4.w};
        int msks[4] = {msk4.x, msk4.y, msk4.z, msk4.w};

#pragma unroll
        for (int s = 0; s < 4; ++s) {
            const int tt = t0 + g * 4 + s;
            int lc = labs[s]; if (lc < 0) lc = 0;
            const float mf = (float)msks[s];
            cnt += msks[s];

            float esel = er[s * 7 + 0];
#pragma unroll
            for (int j = 1; j < 7; ++j) esel = (lc == j) ? er[s * 7 + j] : esel;

            if (tt == 0) {
                num += startT[lc] + esel;
            } else {
                num += mf * (transS[lprev * 7 + lc] + esel);
                if (msks[s] > 0) {
                    float e[7];
#pragma unroll
                    for (int j = 0; j < 7; ++j) e[j] = __expf(er[s * 7 + j]);
#pragma unroll
                    for (int i = 0; i < 7; ++i) {
                        float tmp[7];
#pragma unroll
                        for (int j = 0; j < 7; ++j) tmp[j] = 0.0f;
#pragma unroll
                        for (int k = 0; k < 7; ++k) {
                            const float mik = M[i * 7 + k];
#pragma unroll
                            for (int j = 0; j < 7; ++j)
                                tmp[j] = fmaf(mik, W[k * 7 + j], tmp[j]);
                        }
#pragma unroll
                        for (int j = 0; j < 7; ++j) M[i * 7 + j] = tmp[j] * e[j];
                    }
                }
            }
            lprev = lc;
        }
        if (g & 1) {   // rescale every 8 steps; final g=3 normalizes pre-store
            float mx = 1e-30f;
#pragma unroll
            for (int k = 0; k < 49; ++k) mx = fmaxf(mx, M[k]);
            const float inv = 1.0f / mx;
#pragma unroll
            for (int k = 0; k < 49; ++k) M[k] *= inv;
            logscale += __logf(mx);
        }
    }

    // [c][k][r]: r lane-consecutive -> 128B coalesced stores
#pragma unroll
    for (int k = 0; k < 49; ++k)
        Mh[((size_t)c * 49 + k) * Bsz + r] = __float2half(M[k]);
    lsbuf[c * Bsz + r]  = logscale;
    numbuf[c * Bsz + r] = num;
    cntbuf[c * Bsz + r] = cnt;
}

__global__ __launch_bounds__(64) void crf_chain_kernel(
    const float* __restrict__ em, const int* __restrict__ labels,
    const float* __restrict__ startT, const float* __restrict__ endT,
    const __half* __restrict__ Mh, const float* __restrict__ lsbuf,
    const float* __restrict__ numbuf, const int* __restrict__ cntbuf,
    float* __restrict__ out)
{
    const int r = blockIdx.x * 64 + threadIdx.x;

    float va[7];
#pragma unroll
    for (int j = 0; j < 7; ++j)
        va[j] = __expf(startT[j] + em[(size_t)r * (Tsz * NTG) + j]);

    float ls = 0.0f, num = 0.0f;
    int cnt = 0;

    float bufA[49], bufB[49];

#define LOADC(buf, cc) {                                                   \
    const int _c = (cc);                                                   \
    _Pragma("unroll")                                                      \
    for (int k = 0; k < 49; ++k)                                           \
        buf[k] = __half2float(Mh[((size_t)_c * 49 + k) * Bsz + r]);        \
    ls  += lsbuf[_c * Bsz + r];                                            \
    num += numbuf[_c * Bsz + r];                                           \
    cnt += cntbuf[_c * Bsz + r]; }

#define STEP(buf) {                                                        \
    float nv[7];                                                           \
    _Pragma("unroll")                                                      \
    for (int j = 0; j < 7; ++j) nv[j] = 0.0f;                              \
    _Pragma("unroll")                                                      \
    for (int i = 0; i < 7; ++i) {                                          \
        const float vi = va[i];                                            \
        _Pragma("unroll")                                                  \
        for (int j = 0; j < 7; ++j)                                        \
            nv[j] = fmaf(vi, buf[i * 7 + j], nv[j]);                       \
    }                                                                      \
    float mx = 1e-30f;                                                     \
    _Pragma("unroll")                                                      \
    for (int j = 0; j < 7; ++j) mx = fmaxf(mx, nv[j]);                     \
    const float inv = 1.0f / mx;                                           \
    _Pragma("unroll")                                                      \
    for (int j = 0; j < 7; ++j) va[j] = nv[j] * inv;                       \
    ls += __logf(mx); }

    LOADC(bufA, 0);
    for (int p = 0; p < NCH / 2; ++p) {
        LOADC(bufB, 2 * p + 1);
        STEP(bufA);
        if (p < NCH / 2 - 1) LOADC(bufA, 2 * p + 2);
        STEP(bufB);
    }
#undef LOADC
#undef STEP

    float dsum = 0.0f;
#pragma unroll
    for (int j = 0; j < 7; ++j) dsum += va[j] * __expf(endT[j]);
    const float den = ls + __logf(dsum);

    int se = cnt - 1; if (se < 0) se = 0;
    int lt = labels[r * Tsz + se]; if (lt < 0) lt = 0;
    num += endT[lt];

    float val = den - num;
#pragma unroll
    for (int m = 1; m < 64; m <<= 1) val += __shfl_xor(val, m, 64);
    if (threadIdx.x == 0) atomicAdd(out, val);
}

extern "C" void kernel_launch(void* const* d_in, const int* in_sizes, int n_in,
                              void* d_out, int out_size, void* d_ws, size_t ws_size,
                              hipStream_t stream) {
    const float* em     = (const float*)d_in[0];
    const int*   labels = (const int*)d_in[1];
    const int*   mask   = (const int*)d_in[2];
    const float* startT = (const float*)d_in[3];
    const float* endT   = (const float*)d_in[4];
    const float* trans  = (const float*)d_in[5];
    float* out = (float*)d_out;

    __half* Mh    = (__half*)d_ws;                          // 32*49*8192*2B = 25.7MB
    float*  lsbuf = (float*)(Mh + (size_t)NCH * 49 * Bsz);  // 1MB
    float*  numbuf = lsbuf + (size_t)NCH * Bsz;             // 1MB
    int*    cntbuf = (int*)(numbuf + (size_t)NCH * Bsz);    // 1MB
    (void)in_sizes; (void)n_in; (void)out_size; (void)ws_size;

    hipMemsetAsync(out, 0, sizeof(float), stream);

    crf_op_kernel<<<(Bsz * NCH) / 256, 256, 0, stream>>>(
        em, labels, mask, startT, trans, Mh, lsbuf, numbuf, cntbuf);
    crf_chain_kernel<<<Bsz / 64, 64, 0, stream>>>(
        em, labels, startT, endT, Mh, lsbuf, numbuf, cntbuf, out);
}

// Round 7
// 237.808 us; speedup vs baseline: 2.4511x; 1.8101x over previous
//
#include <hip/hip_runtime.h>

// CRF NLL, B=8192, T=512, NT=7. Single fused kernel:
// Block = 8 rows x 32 chunks (256 threads).
// Phase 1: thread = (row, 16-step chunk): 7x7 linear-domain transfer operator
//          in registers + numerator partials (343 fma/step).
// Phase 2: 5-level pairwise tree merge. Operators stay in registers; at each
//          level the "B" partner dumps its matrix to LDS, survivor multiplies
//          (343 fma) and renormalizes. 1 barrier/level.
// Finale:  row-leader threads apply alpha0, end transitions, numerator.
// Tiny reduce kernel sums 1024 block partials into d_out.

#define Bsz 8192
#define Tsz 512
#define NTG 7
#define NCH 32
#define CS  16
#define RPB 8
#define THB 256

__device__ __forceinline__ float rfl(float x) {
    return __int_as_float(__builtin_amdgcn_readfirstlane(__float_as_int(x)));
}

__global__ __launch_bounds__(THB) void crf_fused_kernel(
    const float* __restrict__ em, const int* __restrict__ labels,
    const int* __restrict__ mask, const float* __restrict__ startT,
    const float* __restrict__ endT, const float* __restrict__ trans,
    float* __restrict__ blockpart)
{
    __shared__ float ldsM[THB * 49];    // 50176 B
    __shared__ float ldsLs[THB];
    __shared__ float ldsNum[THB];
    __shared__ int   ldsCnt[THB];
    __shared__ float transS[49];
    __shared__ float rowval[RPB];

    const int t  = threadIdx.x;
    const int c  = t & (NCH - 1);      // chunk within row
    const int rl = t >> 5;             // row within block
    const int r  = blockIdx.x * RPB + rl;

    if (t < 49) transS[t] = trans[t];
    __syncthreads();

    // W = exp(trans), wave-uniform -> SGPRs
    float W[49];
#pragma unroll
    for (int k = 0; k < 49; ++k) W[k] = rfl(__expf(trans[k]));

    // ---- Phase 1: per-(row,chunk) operator over CS=16 steps ----
    float M[49];
#pragma unroll
    for (int k = 0; k < 49; ++k) M[k] = 0.0f;
#pragma unroll
    for (int i = 0; i < 7; ++i) M[i * 7 + i] = 1.0f;

    float logscale = 0.0f, num = 0.0f;
    int cnt = 0;

    const int t0 = c * CS;
    const float* emr  = em + (size_t)r * (Tsz * NTG) + (size_t)t0 * NTG; // 448B aligned
    const int*   labr = labels + r * Tsz + t0;
    const int*   mskr = mask   + r * Tsz + t0;

    int lprev = 0;
    if (c > 0) { lprev = labr[-1]; if (lprev < 0) lprev = 0; }

#pragma unroll
    for (int g = 0; g < CS / 4; ++g) {
        float er[28];
        const float4* ep = (const float4*)(emr + g * 28);
#pragma unroll
        for (int q = 0; q < 7; ++q) {
            float4 v = ep[q];
            er[4 * q + 0] = v.x; er[4 * q + 1] = v.y;
            er[4 * q + 2] = v.z; er[4 * q + 3] = v.w;
        }
        int4 lab4 = *(const int4*)(labr + g * 4);
        int4 msk4 = *(const int4*)(mskr + g * 4);
        int labs[4] = {lab4.x, lab4.y, lab4.z, lab4.w};
        int msks[4] = {msk4.x, msk4.y, msk4.z, msk4.w};

#pragma unroll
        for (int s = 0; s < 4; ++s) {
            const int tt = t0 + g * 4 + s;
            int lc = labs[s]; if (lc < 0) lc = 0;
            const float mf = (float)msks[s];
            cnt += msks[s];

            float esel = er[s * 7 + 0];
#pragma unroll
            for (int j = 1; j < 7; ++j) esel = (lc == j) ? er[s * 7 + j] : esel;

            if (tt == 0) {
                num += startT[lc] + esel;
            } else {
                num += mf * (transS[lprev * 7 + lc] + esel);
                if (msks[s] > 0) {
                    float e[7];
#pragma unroll
                    for (int j = 0; j < 7; ++j) e[j] = __expf(er[s * 7 + j]);
#pragma unroll
                    for (int i = 0; i < 7; ++i) {
                        float tmp[7];
#pragma unroll
                        for (int j = 0; j < 7; ++j) tmp[j] = 0.0f;
#pragma unroll
                        for (int k = 0; k < 7; ++k) {
                            const float mik = M[i * 7 + k];
#pragma unroll
                            for (int j = 0; j < 7; ++j)
                                tmp[j] = fmaf(mik, W[k * 7 + j], tmp[j]);
                        }
#pragma unroll
                        for (int j = 0; j < 7; ++j) M[i * 7 + j] = tmp[j] * e[j];
                    }
                }
            }
            lprev = lc;
        }
        if (g & 1) {   // rescale every 8 steps; g=3 normalizes before phase 2
            float mx = 1e-30f;
#pragma unroll
            for (int k = 0; k < 49; ++k) mx = fmaxf(mx, M[k]);
            const float inv = 1.0f / mx;
#pragma unroll
            for (int k = 0; k < 49; ++k) M[k] *= inv;
            logscale += __logf(mx);
        }
    }

    ldsNum[t] = num;
    ldsCnt[t] = cnt;
    // (barrier inside level-1 write covers visibility of ldsNum/ldsCnt/ldsLs)

    // ---- Phase 2: 5-level pairwise tree merge ----
    float ls = logscale;
    ldsLs[t] = ls;
#pragma unroll
    for (int L = 1; L <= 5; ++L) {
        const int half = 1 << (L - 1);
        const int m    = (1 << L) - 1;
        const bool isB = (c & m) == half;   // provides right operand, retires
        const bool isA = (c & m) == 0;      // survivor

        if (isB) {
#pragma unroll
            for (int k = 0; k < 49; ++k) ldsM[t * 49 + k] = M[k];
            ldsLs[t] = ls;
        }
        __syncthreads();
        if (isA) {
            float Bm[49];
#pragma unroll
            for (int k = 0; k < 49; ++k) Bm[k] = ldsM[(t + half) * 49 + k];
#pragma unroll
            for (int i = 0; i < 7; ++i) {
                float tmp[7];
#pragma unroll
                for (int j = 0; j < 7; ++j) tmp[j] = 0.0f;
#pragma unroll
                for (int k = 0; k < 7; ++k) {
                    const float mik = M[i * 7 + k];
#pragma unroll
                    for (int j = 0; j < 7; ++j)
                        tmp[j] = fmaf(mik, Bm[k * 7 + j], tmp[j]);
                }
#pragma unroll
                for (int j = 0; j < 7; ++j) M[i * 7 + j] = tmp[j];
            }
            float mx = 1e-30f;
#pragma unroll
            for (int k = 0; k < 49; ++k) mx = fmaxf(mx, M[k]);
            const float inv = 1.0f / mx;
#pragma unroll
            for (int k = 0; k < 49; ++k) M[k] *= inv;
            ls += __logf(mx) + ldsLs[t + half];
        }
        // no second barrier: level-(L+1) writes touch only survivor-owned
        // slots, disjoint from the isB slots read at level L.
    }
    __syncthreads();

    // ---- Finale: one thread per row ----
    if (c == 0) {
        const float* em0 = em + (size_t)r * (Tsz * NTG);
        float a0[7];
#pragma unroll
        for (int j = 0; j < 7; ++j) a0[j] = __expf(startT[j] + em0[j]);
        float nv[7];
#pragma unroll
        for (int j = 0; j < 7; ++j) nv[j] = 0.0f;
#pragma unroll
        for (int i = 0; i < 7; ++i) {
            const float ai = a0[i];
#pragma unroll
            for (int j = 0; j < 7; ++j)
                nv[j] = fmaf(ai, M[i * 7 + j], nv[j]);
        }
        float dsum = 0.0f;
#pragma unroll
        for (int j = 0; j < 7; ++j) dsum += nv[j] * __expf(endT[j]);
        const float den = ls + __logf(dsum);

        float numT = 0.0f; int cntT = 0;
        for (int q = 0; q < NCH; ++q) {
            numT += ldsNum[rl * NCH + q];
            cntT += ldsCnt[rl * NCH + q];
        }
        int se = cntT - 1; if (se < 0) se = 0;
        int lt = labels[r * Tsz + se]; if (lt < 0) lt = 0;
        numT += endT[lt];

        rowval[rl] = den - numT;
    }
    __syncthreads();

    if (t == 0) {
        float s = 0.0f;
#pragma unroll
        for (int k = 0; k < RPB; ++k) s += rowval[k];
        blockpart[blockIdx.x] = s;
    }
}

__global__ __launch_bounds__(256) void crf_reduce_kernel(
    const float* __restrict__ part, float* __restrict__ out)
{
    const int t = threadIdx.x;
    float s = part[t] + part[t + 256] + part[t + 512] + part[t + 768];
    __shared__ float red[256];
    red[t] = s;
    __syncthreads();
    for (int off = 128; off > 0; off >>= 1) {
        if (t < off) red[t] += red[t + off];
        __syncthreads();
    }
    if (t == 0) out[0] = red[0];
}

extern "C" void kernel_launch(void* const* d_in, const int* in_sizes, int n_in,
                              void* d_out, int out_size, void* d_ws, size_t ws_size,
                              hipStream_t stream) {
    const float* em     = (const float*)d_in[0];
    const int*   labels = (const int*)d_in[1];
    const int*   mask   = (const int*)d_in[2];
    const float* startT = (const float*)d_in[3];
    const float* endT   = (const float*)d_in[4];
    const float* trans  = (const float*)d_in[5];
    float* out = (float*)d_out;
    float* blockpart = (float*)d_ws;   // 1024 floats
    (void)in_sizes; (void)n_in; (void)out_size; (void)ws_size;

    crf_fused_kernel<<<Bsz / RPB, THB, 0, stream>>>(
        em, labels, mask, startT, endT, trans, blockpart);
    crf_reduce_kernel<<<1, 256, 0, stream>>>(blockpart, out);
}

// Round 8
// 235.158 us; speedup vs baseline: 2.4787x; 1.0113x over previous
//
#include <hip/hip_runtime.h>

// CRF NLL, B=8192, T=512, NT=7. Single fused kernel:
// Block = 8 rows x 32 chunks (256 threads).
// Phase 1: thread = (row, 16-step chunk): 7x7 linear-domain transfer operator
//          in registers + numerator partials (343 fma/step).
// Phase 2: 5-level pairwise tree merge with COMPRESSED LDS slots (only <=128
//          writers/level; slot = t>>1, unique per level; the only cross-level
//          slot reuse is same-thread read-then-write). LDS 25KB not 50KB ->
//          4 blocks/CU (VGPR-capped) instead of 2-3.
// Finale:  row-leader threads apply alpha0/end/numerator; block partial out.

#define Bsz 8192
#define Tsz 512
#define NTG 7
#define NCH 32
#define CS  16
#define RPB 8
#define THB 256

__device__ __forceinline__ float rfl(float x) {
    return __int_as_float(__builtin_amdgcn_readfirstlane(__float_as_int(x)));
}

__global__ __launch_bounds__(THB) void crf_fused_kernel(
    const float* __restrict__ em, const int* __restrict__ labels,
    const int* __restrict__ mask, const float* __restrict__ startT,
    const float* __restrict__ endT, const float* __restrict__ trans,
    float* __restrict__ blockpart)
{
    __shared__ float ldsM[(THB / 2) * 49];   // 25088 B, compressed slots
    __shared__ float ldsLs[THB];
    __shared__ float ldsNum[THB];
    __shared__ int   ldsCnt[THB];
    __shared__ float transS[49];
    __shared__ float rowval[RPB];

    const int t  = threadIdx.x;
    const int c  = t & (NCH - 1);      // chunk within row
    const int rl = t >> 5;             // row within block
    const int r  = blockIdx.x * RPB + rl;

    if (t < 49) transS[t] = trans[t];
    __syncthreads();

    // W = exp(trans), wave-uniform -> SGPRs
    float W[49];
#pragma unroll
    for (int k = 0; k < 49; ++k) W[k] = rfl(__expf(trans[k]));

    // ---- Phase 1: per-(row,chunk) operator over CS=16 steps ----
    float M[49];
#pragma unroll
    for (int k = 0; k < 49; ++k) M[k] = 0.0f;
#pragma unroll
    for (int i = 0; i < 7; ++i) M[i * 7 + i] = 1.0f;

    float logscale = 0.0f, num = 0.0f;
    int cnt = 0;

    const int t0 = c * CS;
    const float* emr  = em + (size_t)r * (Tsz * NTG) + (size_t)t0 * NTG; // 448B aligned
    const int*   labr = labels + r * Tsz + t0;
    const int*   mskr = mask   + r * Tsz + t0;

    int lprev = 0;
    if (c > 0) { lprev = labr[-1]; if (lprev < 0) lprev = 0; }

#pragma unroll
    for (int g = 0; g < CS / 4; ++g) {
        float er[28];
        const float4* ep = (const float4*)(emr + g * 28);
#pragma unroll
        for (int q = 0; q < 7; ++q) {
            float4 v = ep[q];
            er[4 * q + 0] = v.x; er[4 * q + 1] = v.y;
            er[4 * q + 2] = v.z; er[4 * q + 3] = v.w;
        }
        int4 lab4 = *(const int4*)(labr + g * 4);
        int4 msk4 = *(const int4*)(mskr + g * 4);
        int labs[4] = {lab4.x, lab4.y, lab4.z, lab4.w};
        int msks[4] = {msk4.x, msk4.y, msk4.z, msk4.w};

#pragma unroll
        for (int s = 0; s < 4; ++s) {
            const int tt = t0 + g * 4 + s;
            int lc = labs[s]; if (lc < 0) lc = 0;
            const float mf = (float)msks[s];
            cnt += msks[s];

            float esel = er[s * 7 + 0];
#pragma unroll
            for (int j = 1; j < 7; ++j) esel = (lc == j) ? er[s * 7 + j] : esel;

            if (tt == 0) {
                num += startT[lc] + esel;
            } else {
                num += mf * (transS[lprev * 7 + lc] + esel);
                if (msks[s] > 0) {
                    float e[7];
#pragma unroll
                    for (int j = 0; j < 7; ++j) e[j] = __expf(er[s * 7 + j]);
#pragma unroll
                    for (int i = 0; i < 7; ++i) {
                        float tmp[7];
#pragma unroll
                        for (int j = 0; j < 7; ++j) tmp[j] = 0.0f;
#pragma unroll
                        for (int k = 0; k < 7; ++k) {
                            const float mik = M[i * 7 + k];
#pragma unroll
                            for (int j = 0; j < 7; ++j)
                                tmp[j] = fmaf(mik, W[k * 7 + j], tmp[j]);
                        }
#pragma unroll
                        for (int j = 0; j < 7; ++j) M[i * 7 + j] = tmp[j] * e[j];
                    }
                }
            }
            lprev = lc;
        }
        if (g & 1) {   // rescale every 8 steps; g=3 normalizes before phase 2
            float mx = 1e-30f;
#pragma unroll
            for (int k = 0; k < 49; ++k) mx = fmaxf(mx, M[k]);
            const float inv = 1.0f / mx;
#pragma unroll
            for (int k = 0; k < 49; ++k) M[k] *= inv;
            logscale += __logf(mx);
        }
    }

    ldsNum[t] = num;
    ldsCnt[t] = cnt;
    // (level-1 barrier covers visibility of ldsNum/ldsCnt/ldsLs for finale)

    // ---- Phase 2: 5-level pairwise tree merge, compressed slots ----
    float ls = logscale;
    ldsLs[t] = ls;
#pragma unroll
    for (int L = 1; L <= 5; ++L) {
        const int half = 1 << (L - 1);
        const int m    = (1 << L) - 1;
        const bool isB = (c & m) == half;   // provides right operand, retires
        const bool isA = (c & m) == 0;      // survivor

        if (isB) {
#pragma unroll
            for (int k = 0; k < 49; ++k) ldsM[(t >> 1) * 49 + k] = M[k];
            ldsLs[t] = ls;
        }
        __syncthreads();
        if (isA) {
            float Bm[49];
#pragma unroll
            for (int k = 0; k < 49; ++k) Bm[k] = ldsM[((t + half) >> 1) * 49 + k];
#pragma unroll
            for (int i = 0; i < 7; ++i) {
                float tmp[7];
#pragma unroll
                for (int j = 0; j < 7; ++j) tmp[j] = 0.0f;
#pragma unroll
                for (int k = 0; k < 7; ++k) {
                    const float mik = M[i * 7 + k];
#pragma unroll
                    for (int j = 0; j < 7; ++j)
                        tmp[j] = fmaf(mik, Bm[k * 7 + j], tmp[j]);
                }
#pragma unroll
                for (int j = 0; j < 7; ++j) M[i * 7 + j] = tmp[j];
            }
            float mx = 1e-30f;
#pragma unroll
            for (int k = 0; k < 49; ++k) mx = fmaxf(mx, M[k]);
            const float inv = 1.0f / mx;
#pragma unroll
            for (int k = 0; k < 49; ++k) M[k] *= inv;
            ls += __logf(mx) + ldsLs[t + half];
        }
        // No second barrier: a level-(L+1) B-write can only reuse the slot its
        // own thread just read at level L (read-before-write, sequential);
        // all other level-L reader slots are provably distinct (mod-2^L calc).
    }
    __syncthreads();

    // ---- Finale: one thread per row ----
    if (c == 0) {
        const float* em0 = em + (size_t)r * (Tsz * NTG);
        float a0[7];
#pragma unroll
        for (int j = 0; j < 7; ++j) a0[j] = __expf(startT[j] + em0[j]);
        float nv[7];
#pragma unroll
        for (int j = 0; j < 7; ++j) nv[j] = 0.0f;
#pragma unroll
        for (int i = 0; i < 7; ++i) {
            const float ai = a0[i];
#pragma unroll
            for (int j = 0; j < 7; ++j)
                nv[j] = fmaf(ai, M[i * 7 + j], nv[j]);
        }
        float dsum = 0.0f;
#pragma unroll
        for (int j = 0; j < 7; ++j) dsum += nv[j] * __expf(endT[j]);
        const float den = ls + __logf(dsum);

        float numT = 0.0f; int cntT = 0;
        for (int q = 0; q < NCH; ++q) {
            numT += ldsNum[rl * NCH + q];
            cntT += ldsCnt[rl * NCH + q];
        }
        int se = cntT - 1; if (se < 0) se = 0;
        int lt = labels[r * Tsz + se]; if (lt < 0) lt = 0;
        numT += endT[lt];

        rowval[rl] = den - numT;
    }
    __syncthreads();

    if (t == 0) {
        float s = 0.0f;
#pragma unroll
        for (int k = 0; k < RPB; ++k) s += rowval[k];
        blockpart[blockIdx.x] = s;
    }
}

__global__ __launch_bounds__(256) void crf_reduce_kernel(
    const float* __restrict__ part, float* __restrict__ out)
{
    const int t = threadIdx.x;
    float s = part[t] + part[t + 256] + part[t + 512] + part[t + 768];
    __shared__ float red[256];
    red[t] = s;
    __syncthreads();
    for (int off = 128; off > 0; off >>= 1) {
        if (t < off) red[t] += red[t + off];
        __syncthreads();
    }
    if (t == 0) out[0] = red[0];
}

extern "C" void kernel_launch(void* const* d_in, const int* in_sizes, int n_in,
                              void* d_out, int out_size, void* d_ws, size_t ws_size,
                              hipStream_t stream) {
    const float* em     = (const float*)d_in[0];
    const int*   labels = (const int*)d_in[1];
    const int*   mask   = (const int*)d_in[2];
    const float* startT = (const float*)d_in[3];
    const float* endT   = (const float*)d_in[4];
    const float* trans  = (const float*)d_in[5];
    float* out = (float*)d_out;
    float* blockpart = (float*)d_ws;   // 1024 floats
    (void)in_sizes; (void)n_in; (void)out_size; (void)ws_size;

    crf_fused_kernel<<<Bsz / RPB, THB, 0, stream>>>(
        em, labels, mask, startT, endT, trans, blockpart);
    crf_reduce_kernel<<<1, 256, 0, stream>>>(blockpart, out);
}